// Round 4
// baseline (138.895 us; speedup 1.0000x reference)
//
#include <hip/hip_runtime.h>

// Problem constants (from reference)
#define BB      2
#define CC      256
#define HH      384
#define WW      384
#define N_ACT   16384
#define GRID_N  192                 // index grid; coord = 2*idx (OFFSET=0, STRIDE=2)
#define PLANE_F4 ((HH * WW) / 4)    // 36864 float4 per (b,c) plane
#define ROW_F4   (WW / 4)           // 96 float4 per row
#define COLP    48                  // half-row float4 columns per thread slot
#define SLOTS_PER_PLANE (GRID_N * COLP)  // 9216 thread slots per plane

// Native clang vector type — required by __builtin_nontemporal_load/store.
typedef float  fx4 __attribute__((ext_vector_type(4)));

// --- Kernel 1: winner[cell] = max k writing to that cell (numpy last-wins) --
__global__ void winner_scatter_kernel(const int* __restrict__ idx,
                                      int* __restrict__ winner) {
    int k = blockIdx.x * blockDim.x + threadIdx.x;
    if (k < N_ACT) {
        int iy = idx[2 * k];
        int ix = idx[2 * k + 1];
        atomicMax(&winner[iy * GRID_N + ix], k);
    }
}

// --- Kernel 2: fused copy + scatter-resolve --------------------------------
// One thread per 2-row x 2-float4 patch: rows (2gy, 2gy+1), float4 cols
// cp and cp+48. Even row's lanes [0] (x=4j) and [2] (x=4j+2) map to winner
// cells 2j and 2j+1. 4 NT stream loads + 2 int2 winner loads + <=4 gathers
// + 4 NT stores per thread -> high memory-level parallelism.
__global__ void scatter_main_kernel(const fx4* __restrict__ orig,
                                    const float* __restrict__ x,
                                    const int* __restrict__ winner,
                                    fx4* __restrict__ out) {
    int bc = blockIdx.y;                                   // 0..511
    int q  = blockIdx.x * blockDim.x + threadIdx.x;        // 0..9215
    int gy = q / COLP;                                     // grid row 0..191
    int cp = q - gy * COLP;                                // 0..47

    int rowbase = bc * PLANE_F4 + (gy * 2) * ROW_F4;
    int a0 = rowbase + cp;                                 // even row, col cp
    int a1 = rowbase + cp + COLP;                          // even row, col cp+48
    int b0 = a0 + ROW_F4;                                  // odd row
    int b1 = a1 + ROW_F4;

    // Issue all stream + winner loads up front (independent).
    fx4 vA = __builtin_nontemporal_load(&orig[a0]);
    fx4 vB = __builtin_nontemporal_load(&orig[a1]);
    fx4 vC = __builtin_nontemporal_load(&orig[b0]);
    fx4 vD = __builtin_nontemporal_load(&orig[b1]);
    const int2* wrow2 = reinterpret_cast<const int2*>(winner + gy * GRID_N);
    int2 wA = wrow2[cp];                                   // cells 2cp, 2cp+1
    int2 wB = wrow2[cp + COLP];                            // cells 2cp+96, 2cp+97

    const float* xp = x + bc * N_ACT;
    if (wA.x >= 0) vA[0] = xp[wA.x];
    if (wA.y >= 0) vA[2] = xp[wA.y];
    if (wB.x >= 0) vB[0] = xp[wB.x];
    if (wB.y >= 0) vB[2] = xp[wB.y];

    __builtin_nontemporal_store(vA, &out[a0]);
    __builtin_nontemporal_store(vB, &out[a1]);
    __builtin_nontemporal_store(vC, &out[b0]);
    __builtin_nontemporal_store(vD, &out[b1]);
}

extern "C" void kernel_launch(void* const* d_in, const int* in_sizes, int n_in,
                              void* d_out, int out_size, void* d_ws, size_t ws_size,
                              hipStream_t stream) {
    const float* x    = (const float*)d_in[0];   // [B, C, N_ACT]
    const float* orig = (const float*)d_in[1];   // [B, C, H, W]
    const int*   idx  = (const int*)d_in[2];     // [N_ACT, 2]
    float*       out  = (float*)d_out;           // [B, C, H, W]
    int*         winner = (int*)d_ws;            // GRID_N*GRID_N ints = 147456 B

    // 1. winner map = -1 (0xFF bytes) — async memset is graph-capturable
    (void)hipMemsetAsync(winner, 0xFF, GRID_N * GRID_N * sizeof(int), stream);
    // 2. last-write-wins resolution via atomicMax over k
    winner_scatter_kernel<<<dim3((N_ACT + 255) / 256), dim3(256), 0, stream>>>(idx, winner);
    // 3. fused copy + patch, 2x2-float4 patch per thread
    scatter_main_kernel<<<dim3(SLOTS_PER_PLANE / 256, BB * CC), dim3(256), 0, stream>>>(
        (const fx4*)orig, x, winner, (fx4*)out);
}

// Round 5
// 138.426 us; speedup vs baseline: 1.0034x; 1.0034x over previous
//
#include <hip/hip_runtime.h>

// Problem constants (from reference)
#define BB      2
#define CC      256
#define HH      384
#define WW      384
#define N_ACT   16384
#define GRID_N  192                 // index grid; coord = 2*idx (OFFSET=0, STRIDE=2)
#define PLANE_F4 ((HH * WW) / 4)    // 36864 float4 per (b,c) plane
#define ROW_F4   (WW / 4)           // 96 float4 per row
#define PAIRS_PER_PLANE (PLANE_F4 / 2)   // 18432 row-pair float4 slots

// Native clang vector type — required by __builtin_nontemporal_load.
typedef float  fx4 __attribute__((ext_vector_type(4)));

// --- Kernel 1: winner[cell] = max k writing to that cell (numpy last-wins) --
__global__ void winner_scatter_kernel(const int2* __restrict__ idx,
                                      int* __restrict__ winner) {
    int k = blockIdx.x * blockDim.x + threadIdx.x;
    if (k < N_ACT) {
        int2 p = idx[k];                       // p.x = iy, p.y = ix (coalesced 8B)
        atomicMax(&winner[p.x * GRID_N + p.y], k);
    }
}

// --- Kernel 2: fused copy + scatter-resolve, one thread per row-pair float4 -
// Grid: (PAIRS_PER_PLANE/256, B*C). Thread handles float4 at (2*gy, col) and
// (2*gy+1, col) of its plane. Only the even row can contain active sites
// (lanes [0] at x=4*col and [2] at x=4*col+2).
// NT loads on the read-once orig stream (keep L2 for winner+x);
// NORMAL stores on out (L2 write-back buffers DRAM scheduling — the 7 TB/s
// fill and 6.3 TB/s copy references both use cached stores).
__global__ void scatter_main_kernel(const fx4* __restrict__ orig,
                                    const float* __restrict__ x,
                                    const int* __restrict__ winner,
                                    fx4* __restrict__ out) {
    int bc = blockIdx.y;                                   // 0..511
    int q  = blockIdx.x * blockDim.x + threadIdx.x;        // 0..18431
    int gy  = q / ROW_F4;                                  // grid row 0..191
    int col = q - gy * ROW_F4;                             // float4 col 0..95

    int base = bc * PLANE_F4 + (gy * 2) * ROW_F4 + col;    // even row slot

    // Issue winner + both stream loads up front (independent).
    const int2* wrow2 = reinterpret_cast<const int2*>(winner + gy * GRID_N);
    int2 w = wrow2[col];                                   // cells gx=2col, 2col+1
    fx4 ve = __builtin_nontemporal_load(&orig[base]);
    fx4 vo = __builtin_nontemporal_load(&orig[base + ROW_F4]);

    if (w.x >= 0 || w.y >= 0) {
        const float* xp = x + bc * N_ACT;
        if (w.x >= 0) ve[0] = xp[w.x];
        if (w.y >= 0) ve[2] = xp[w.y];
    }

    out[base] = ve;
    out[base + ROW_F4] = vo;
}

extern "C" void kernel_launch(void* const* d_in, const int* in_sizes, int n_in,
                              void* d_out, int out_size, void* d_ws, size_t ws_size,
                              hipStream_t stream) {
    const float* x    = (const float*)d_in[0];   // [B, C, N_ACT]
    const float* orig = (const float*)d_in[1];   // [B, C, H, W]
    const int*   idx  = (const int*)d_in[2];     // [N_ACT, 2]
    float*       out  = (float*)d_out;           // [B, C, H, W]
    int*         winner = (int*)d_ws;            // GRID_N*GRID_N ints = 147456 B

    // 1. winner map = -1 (0xFF bytes) — async memset is graph-capturable
    (void)hipMemsetAsync(winner, 0xFF, GRID_N * GRID_N * sizeof(int), stream);
    // 2. last-write-wins resolution via atomicMax over k
    winner_scatter_kernel<<<dim3((N_ACT + 255) / 256), dim3(256), 0, stream>>>(
        (const int2*)idx, winner);
    // 3. fused copy + patch, row-pair threads
    scatter_main_kernel<<<dim3(PAIRS_PER_PLANE / 256, BB * CC), dim3(256), 0, stream>>>(
        (const fx4*)orig, x, winner, (fx4*)out);
}